// Round 13
// baseline (182.033 us; speedup 1.0000x reference)
//
#include <hip/hip_runtime.h>
#include <hip/hip_bf16.h>
#include <hip/hip_fp16.h>

// ---------------- constants ----------------
#define N_NODES 50000
#define N_EDGES 600000
#define N_GRAPHS 64
#define P4C 64  // chunks per graph in fused layer4+pool

typedef __attribute__((ext_vector_type(8))) short bf16x8;
typedef __attribute__((ext_vector_type(4))) float f32x4;

// ---------------- bf16 helpers (round-to-nearest-even) ----------------
__device__ __forceinline__ unsigned short f2bf(float f) {
    unsigned int u = __float_as_uint(f);
    unsigned int r = u + 0x7fffu + ((u >> 16) & 1u);
    return (unsigned short)(r >> 16);
}
__device__ __forceinline__ float bf_lo(unsigned int u) { return __uint_as_float(u << 16); }
__device__ __forceinline__ float bf_hi(unsigned int u) { return __uint_as_float(u & 0xffff0000u); }
__device__ __forceinline__ float bf1(unsigned short s) {
    return __uint_as_float((unsigned int)s << 16);
}
// packed csr entry: (src << 16) | f16(norm)
__device__ __forceinline__ float pnorm(unsigned int e) {
    return __half2float(__ushort_as_half((unsigned short)(e & 0xffffu)));
}

// ---------------- fused degree count (int4-vectorized) + weight repack ----------------
__device__ __forceinline__ void wprep_one(const float* W, unsigned short* Wp, int F, int idx) {
    int i = idx & 7;
    int lane = (idx >> 3) & 63;
    int ks = (idx >> 9) & 3;
    int ct = idx >> 11;
    int k = ks * 32 + (lane >> 4) * 8 + i;
    int col = ct * 16 + (lane & 15);
    Wp[idx] = f2bf(W[(size_t)k * F + col]);
}

#define DEGB4 ((N_EDGES + 1023) / 1024)  // 586 (4 edges per thread)

__global__ __launch_bounds__(256) void deg_wprep(const int* __restrict__ dst,
                                                 int* __restrict__ degi, int E,
                                                 const float* __restrict__ W1,
                                                 const float* __restrict__ W2,
                                                 const float* __restrict__ W3,
                                                 const float* __restrict__ W4,
                                                 unsigned short* __restrict__ Wp1,
                                                 unsigned short* __restrict__ Wp2,
                                                 unsigned short* __restrict__ Wp3,
                                                 unsigned short* __restrict__ Wp4) {
    int bid = blockIdx.x;
    if (bid < DEGB4) {
        int i4 = bid * 1024 + threadIdx.x * 4;
        if (i4 + 4 <= E) {
            int4 d = *reinterpret_cast<const int4*>(dst + i4);
            atomicAdd(&degi[d.x], 1);
            atomicAdd(&degi[d.y], 1);
            atomicAdd(&degi[d.z], 1);
            atomicAdd(&degi[d.w], 1);
        } else {
            for (int i = i4; i < E; ++i) atomicAdd(&degi[dst[i]], 1);
        }
    } else {
        int wb = bid - DEGB4;
        if (wb < 64) wprep_one(W1, Wp1, 128, wb * 256 + threadIdx.x);
        else if (wb < 128) wprep_one(W2, Wp2, 128, (wb - 64) * 256 + threadIdx.x);
        else if (wb < 192) wprep_one(W3, Wp3, 128, (wb - 128) * 256 + threadIdx.x);
        else wprep_one(W4, Wp4, 64, (wb - 192) * 256 + threadIdx.x);
    }
}

// ---------------- prefix scan (3-kernel hierarchical; proven ~8us) ----------------
__global__ __launch_bounds__(256) void scan_block(const int* __restrict__ in,
                                                  int* __restrict__ excl,
                                                  int* __restrict__ bsum,
                                                  float* __restrict__ dis, int N) {
    __shared__ int s[256];
    int i = blockIdx.x * 256 + threadIdx.x;
    int v = (i < N) ? in[i] : 0;
    s[threadIdx.x] = v;
    __syncthreads();
#pragma unroll
    for (int off = 1; off < 256; off <<= 1) {
        int t = (threadIdx.x >= off) ? s[threadIdx.x - off] : 0;
        __syncthreads();
        s[threadIdx.x] += t;
        __syncthreads();
    }
    if (i < N) {
        excl[i] = s[threadIdx.x] - v;
        dis[i] = rsqrtf((float)v + 1.0f);
    }
    if (threadIdx.x == 255) bsum[blockIdx.x] = s[255];
}

__global__ __launch_bounds__(256) void scan_top(const int* __restrict__ bsum,
                                                int* __restrict__ boff, int NB,
                                                const int* __restrict__ batch,
                                                int* __restrict__ gstart, int N) {
    __shared__ int s[256];
    int v = (threadIdx.x < NB) ? bsum[threadIdx.x] : 0;
    s[threadIdx.x] = v;
    __syncthreads();
#pragma unroll
    for (int off = 1; off < 256; off <<= 1) {
        int t = (threadIdx.x >= off) ? s[threadIdx.x - off] : 0;
        __syncthreads();
        s[threadIdx.x] += t;
        __syncthreads();
    }
    if (threadIdx.x < NB) boff[threadIdx.x] = s[threadIdx.x] - v;

    int g = threadIdx.x;
    if (g <= N_GRAPHS) {
        int lo = 0, hi = N;
        while (lo < hi) {
            int mid = (lo + hi) >> 1;
            if (batch[mid] < g) lo = mid + 1; else hi = mid;
        }
        gstart[g] = lo;
    }
}

__global__ __launch_bounds__(256) void scan_fix(const int* __restrict__ excl,
                                                const int* __restrict__ boff,
                                                int* __restrict__ rowptr,
                                                int* __restrict__ cursor, int N, int E) {
    int i = blockIdx.x * 256 + threadIdx.x;
    if (i < N) {
        int r = excl[i] + boff[blockIdx.x];
        rowptr[i] = r;
        cursor[i] = r;
    }
    if (i == 0) rowptr[N] = E;
}

// ---------------- FUSED: mm1 + XCD-partitioned CSR fill ----------------
#define MM1B ((N_NODES + 63) / 64)        // 782
#define CSRB ((N_EDGES + 255) / 256)      // 2344

__global__ __launch_bounds__(256) void csrfill_mm1(const int* __restrict__ src,
                                                   const int* __restrict__ dst,
                                                   const float* __restrict__ dis,
                                                   int* __restrict__ cursor,
                                                   unsigned int* __restrict__ csr, int E,
                                                   const float* __restrict__ Xf,
                                                   const unsigned short* __restrict__ Wp,
                                                   unsigned short* __restrict__ T, int N) {
    if (blockIdx.x >= MM1B) {
        // ---- CSR fill (XCD-partitioned by dst range) ----
        const int part = blockIdx.x & 7;
        const int ch = (blockIdx.x - MM1B) >> 3;
        int e = ch * 256 + threadIdx.x;
        if (e >= E) return;
        int d = dst[e];
        if ((d * 8) / N_NODES != part) return;
        int s = src[e];
        float nrm = dis[s] * dis[d];
        unsigned short hb = __half_as_ushort(__float2half(nrm));
        int pos = atomicAdd(&cursor[d], 1);
        csr[pos] = ((unsigned int)s << 16) | (unsigned int)hb;
        return;
    }
    // ---- mm1 ----
    const int lane = threadIdx.x & 63;
    const int wave = threadIdx.x >> 6;
    const int r0 = blockIdx.x * 64 + wave * 16;
    const int kg = lane >> 4;
    const int rdrow = min(r0 + (lane & 15), N - 1);
    const float* xr = Xf + (size_t)rdrow * 128;

    bf16x8 a[4];
#pragma unroll
    for (int ks = 0; ks < 4; ++ks) {
        const int kb = ks * 32 + kg * 8;
        float4 x0 = *reinterpret_cast<const float4*>(xr + kb);
        float4 x1 = *reinterpret_cast<const float4*>(xr + kb + 4);
        float v[8] = {x0.x, x0.y, x0.z, x0.w, x1.x, x1.y, x1.z, x1.w};
#pragma unroll
        for (int i = 0; i < 8; ++i) a[ks][i] = (short)f2bf(v[i]);
    }

#pragma unroll
    for (int ct = 0; ct < 8; ++ct) {
        f32x4 acc = {0.f, 0.f, 0.f, 0.f};
#pragma unroll
        for (int ks = 0; ks < 4; ++ks) {
            bf16x8 b = *reinterpret_cast<const bf16x8*>(Wp + ((size_t)(ct * 4 + ks) * 64 + lane) * 8);
            acc = __builtin_amdgcn_mfma_f32_16x16x32_bf16(a[ks], b, acc, 0, 0, 0);
        }
        const int col = ct * 16 + (lane & 15);
#pragma unroll
        for (int r = 0; r < 4; ++r) {
            const int rowm = r0 + kg * 4 + r;
            if (rowm < N) T[(size_t)rowm * 128 + col] = f2bf(acc[r]);
        }
    }
}

// ---------------- dual-node combined-stream gather (128-feat rows) ----------------
__device__ __forceinline__ void gather128x2(int beg, int mid, int end,
                                            const unsigned int* __restrict__ csr,
                                            const unsigned short* __restrict__ T, int lane,
                                            float& ax0, float& ay0, float& ax1, float& ay1) {
    int p = beg;
    for (; p + 8 <= end; p += 8) {
        unsigned int e0 = csr[p], e1 = csr[p + 1], e2 = csr[p + 2], e3 = csr[p + 3];
        unsigned int e4 = csr[p + 4], e5 = csr[p + 5], e6 = csr[p + 6], e7 = csr[p + 7];
        unsigned int r0 = *reinterpret_cast<const unsigned int*>(T + (size_t)(e0 >> 16) * 128 + lane * 2);
        unsigned int r1 = *reinterpret_cast<const unsigned int*>(T + (size_t)(e1 >> 16) * 128 + lane * 2);
        unsigned int r2 = *reinterpret_cast<const unsigned int*>(T + (size_t)(e2 >> 16) * 128 + lane * 2);
        unsigned int r3 = *reinterpret_cast<const unsigned int*>(T + (size_t)(e3 >> 16) * 128 + lane * 2);
        unsigned int r4 = *reinterpret_cast<const unsigned int*>(T + (size_t)(e4 >> 16) * 128 + lane * 2);
        unsigned int r5 = *reinterpret_cast<const unsigned int*>(T + (size_t)(e5 >> 16) * 128 + lane * 2);
        unsigned int r6 = *reinterpret_cast<const unsigned int*>(T + (size_t)(e6 >> 16) * 128 + lane * 2);
        unsigned int r7 = *reinterpret_cast<const unsigned int*>(T + (size_t)(e7 >> 16) * 128 + lane * 2);
#define ACC8(K)                                                                  \
        {                                                                        \
            float n = pnorm(e##K);                                               \
            float na = (p + K < mid) ? n : 0.0f;                                 \
            float nb = (p + K < mid) ? 0.0f : n;                                 \
            ax0 = fmaf(na, bf_lo(r##K), ax0); ay0 = fmaf(na, bf_hi(r##K), ay0);  \
            ax1 = fmaf(nb, bf_lo(r##K), ax1); ay1 = fmaf(nb, bf_hi(r##K), ay1);  \
        }
        ACC8(0) ACC8(1) ACC8(2) ACC8(3) ACC8(4) ACC8(5) ACC8(6) ACC8(7)
#undef ACC8
    }
    for (; p + 4 <= end; p += 4) {
        unsigned int e0 = csr[p], e1 = csr[p + 1], e2 = csr[p + 2], e3 = csr[p + 3];
        unsigned int r0 = *reinterpret_cast<const unsigned int*>(T + (size_t)(e0 >> 16) * 128 + lane * 2);
        unsigned int r1 = *reinterpret_cast<const unsigned int*>(T + (size_t)(e1 >> 16) * 128 + lane * 2);
        unsigned int r2 = *reinterpret_cast<const unsigned int*>(T + (size_t)(e2 >> 16) * 128 + lane * 2);
        unsigned int r3 = *reinterpret_cast<const unsigned int*>(T + (size_t)(e3 >> 16) * 128 + lane * 2);
#define ACC4(K)                                                                  \
        {                                                                        \
            float n = pnorm(e##K);                                               \
            float na = (p + K < mid) ? n : 0.0f;                                 \
            float nb = (p + K < mid) ? 0.0f : n;                                 \
            ax0 = fmaf(na, bf_lo(r##K), ax0); ay0 = fmaf(na, bf_hi(r##K), ay0);  \
            ax1 = fmaf(nb, bf_lo(r##K), ax1); ay1 = fmaf(nb, bf_hi(r##K), ay1);  \
        }
        ACC4(0) ACC4(1) ACC4(2) ACC4(3)
#undef ACC4
    }
    for (; p < end; ++p) {
        unsigned int e = csr[p];
        unsigned int r = *reinterpret_cast<const unsigned int*>(T + (size_t)(e >> 16) * 128 + lane * 2);
        float n = pnorm(e);
        float na = (p < mid) ? n : 0.0f;
        float nb = (p < mid) ? 0.0f : n;
        ax0 = fmaf(na, bf_lo(r), ax0); ay0 = fmaf(na, bf_hi(r), ay0);
        ax1 = fmaf(nb, bf_lo(r), ax1); ay1 = fmaf(nb, bf_hi(r), ay1);
    }
}

// ---------------- FUSED: agg(layer i) + relu + mm(layer i+1) ----------------
template <int FOUT>
__global__ __launch_bounds__(512) void aggmm(const int* __restrict__ rowptr,
                                             const unsigned int* __restrict__ csr,
                                             const float* __restrict__ dis,
                                             const float* __restrict__ b,
                                             const unsigned short* __restrict__ T,
                                             const unsigned short* __restrict__ Wp,
                                             unsigned short* __restrict__ Tout, int N) {
    __shared__ unsigned short hl[16][136];
    const int lane = threadIdx.x & 63;
    const int wave = threadIdx.x >> 6;
    const int r0 = blockIdx.x * 16;
    const float2 bb = *reinterpret_cast<const float2*>(b + lane * 2);

    const int n0 = __builtin_amdgcn_readfirstlane(r0 + wave * 2);
    const int beg = rowptr[n0];
    const int mid = rowptr[n0 + 1];
    const int end = rowptr[n0 + 2];
    const float d0 = dis[n0], d1 = dis[n0 + 1];

    unsigned int s0 = *reinterpret_cast<const unsigned int*>(T + (size_t)n0 * 128 + lane * 2);
    unsigned int s1 = *reinterpret_cast<const unsigned int*>(T + (size_t)(n0 + 1) * 128 + lane * 2);
    float ax0 = fmaf(bf_lo(s0), d0 * d0, bb.x);
    float ay0 = fmaf(bf_hi(s0), d0 * d0, bb.y);
    float ax1 = fmaf(bf_lo(s1), d1 * d1, bb.x);
    float ay1 = fmaf(bf_hi(s1), d1 * d1, bb.y);

    gather128x2(beg, mid, end, csr, T, lane, ax0, ay0, ax1, ay1);

    *reinterpret_cast<unsigned int*>(&hl[wave * 2 + 0][lane * 2]) =
        ((unsigned int)f2bf(ay0) << 16) | (unsigned int)f2bf(ax0);
    *reinterpret_cast<unsigned int*>(&hl[wave * 2 + 1][lane * 2]) =
        ((unsigned int)f2bf(ay1) << 16) | (unsigned int)f2bf(ax1);
    __syncthreads();

    constexpr int NCT = FOUT / 16;  // 8 (F=128) or 4 (F=64)
    if (wave < NCT) {
        const int kg = lane >> 4;
        bf16x8 a[4];
#pragma unroll
        for (int ks = 0; ks < 4; ++ks) {
            bf16x8 av = *reinterpret_cast<const bf16x8*>(&hl[lane & 15][ks * 32 + kg * 8]);
#pragma unroll
            for (int i = 0; i < 8; ++i) av[i] = (av[i] < 0) ? (short)0 : av[i];
            a[ks] = av;
        }

        const int ct = wave;
        f32x4 acc = {0.f, 0.f, 0.f, 0.f};
#pragma unroll
        for (int ks = 0; ks < 4; ++ks) {
            bf16x8 bfr = *reinterpret_cast<const bf16x8*>(Wp + ((size_t)(ct * 4 + ks) * 64 + lane) * 8);
            acc = __builtin_amdgcn_mfma_f32_16x16x32_bf16(a[ks], bfr, acc, 0, 0, 0);
        }
        const int col = ct * 16 + (lane & 15);
#pragma unroll
        for (int r = 0; r < 4; ++r) {
            Tout[(size_t)(r0 + kg * 4 + r) * FOUT + col] = f2bf(acc[r]);
        }
    }
}

// ---------------- FUSED layer-4 agg + mean pool (algebraic fusion) ----------------
// sum_{i in g} agg_i[f] = sum_i T4_i[f]*dis_i^2 + cnt_g*b4[f]
//                        + sum_{e: dst in g} norm_e * T4[src_e][f]
// graph g's edge set = contiguous csr range [rowptr[gstart[g]], rowptr[gstart[g+1]]).
// grid = N_GRAPHS * P4C blocks, 256 thr (4 waves), lane = feature.
__global__ __launch_bounds__(256) void pool4(const int* __restrict__ rowptr,
                                             const unsigned int* __restrict__ csr,
                                             const float* __restrict__ dis,
                                             const unsigned short* __restrict__ T,
                                             const int* __restrict__ gstart,
                                             float* __restrict__ partial) {
    const int g = blockIdx.x / P4C;
    const int c = blockIdx.x % P4C;
    const int lane = threadIdx.x & 63;
    const int wave = threadIdx.x >> 6;
    const int nb = gstart[g], ne = gstart[g + 1];

    float acc = 0.0f;

    // self-loop part: chunk the node range
    {
        const int len = ne - nb;
        const int cs = (len + P4C - 1) / P4C;
        const int a = nb + c * cs;
        const int bnd = min(a + cs, ne);
        for (int n = a + wave; n < bnd; n += 4) {
            float d = dis[n];
            acc = fmaf(bf1(T[(size_t)n * 64 + lane]) * d, d, acc);
        }
    }

    // edge part: chunk the graph's contiguous edge range
    {
        const int eb = rowptr[nb], ee = rowptr[ne];
        const int len = ee - eb;
        const int cs = (len + P4C - 1) / P4C;
        const int a = eb + c * cs;
        const int bnd = min(a + cs, ee);
        int p = a + wave;
        for (; p + 8 * 4 <= bnd; p += 32) {
            unsigned int e0 = csr[p], e1 = csr[p + 4], e2 = csr[p + 8], e3 = csr[p + 12];
            unsigned int e4 = csr[p + 16], e5 = csr[p + 20], e6 = csr[p + 24], e7 = csr[p + 28];
            unsigned short v0 = T[(size_t)(e0 >> 16) * 64 + lane];
            unsigned short v1 = T[(size_t)(e1 >> 16) * 64 + lane];
            unsigned short v2 = T[(size_t)(e2 >> 16) * 64 + lane];
            unsigned short v3 = T[(size_t)(e3 >> 16) * 64 + lane];
            unsigned short v4 = T[(size_t)(e4 >> 16) * 64 + lane];
            unsigned short v5 = T[(size_t)(e5 >> 16) * 64 + lane];
            unsigned short v6 = T[(size_t)(e6 >> 16) * 64 + lane];
            unsigned short v7 = T[(size_t)(e7 >> 16) * 64 + lane];
            acc = fmaf(pnorm(e0), bf1(v0), acc);
            acc = fmaf(pnorm(e1), bf1(v1), acc);
            acc = fmaf(pnorm(e2), bf1(v2), acc);
            acc = fmaf(pnorm(e3), bf1(v3), acc);
            acc = fmaf(pnorm(e4), bf1(v4), acc);
            acc = fmaf(pnorm(e5), bf1(v5), acc);
            acc = fmaf(pnorm(e6), bf1(v6), acc);
            acc = fmaf(pnorm(e7), bf1(v7), acc);
        }
        for (; p < bnd; p += 4) {
            unsigned int e = csr[p];
            acc = fmaf(pnorm(e), bf1(T[(size_t)(e >> 16) * 64 + lane]), acc);
        }
    }

    __shared__ float s[4][64];
    s[wave][lane] = acc;
    __syncthreads();
    if (wave == 0)
        partial[(size_t)blockIdx.x * 64 + lane] =
            s[0][lane] + s[1][lane] + s[2][lane] + s[3][lane];
}

__global__ __launch_bounds__(64) void pool_fin4(const float* __restrict__ partial,
                                                const int* __restrict__ gstart,
                                                const float* __restrict__ b4,
                                                float* __restrict__ out) {
    const int g = blockIdx.x;
    const int lane = threadIdx.x;
    float v = 0.0f;
#pragma unroll 8
    for (int c = 0; c < P4C; ++c) v += partial[(size_t)(g * P4C + c) * 64 + lane];
    float cnt = (float)(gstart[g + 1] - gstart[g]);
    v += cnt * b4[lane];
    out[g * 64 + lane] = v / fmaxf(cnt, 1.0f);
}

// ---------------- launch ----------------
extern "C" void kernel_launch(void* const* d_in, const int* in_sizes, int n_in,
                              void* d_out, int out_size, void* d_ws, size_t ws_size,
                              hipStream_t stream) {
    const float* x = (const float*)d_in[0];
    const int* ei = (const int*)d_in[1];
    const int* batch = (const int*)d_in[2];
    const float* W1 = (const float*)d_in[3];
    const float* b1 = (const float*)d_in[4];
    const float* W2 = (const float*)d_in[5];
    const float* b2 = (const float*)d_in[6];
    const float* W3 = (const float*)d_in[7];
    const float* b3 = (const float*)d_in[8];
    const float* W4 = (const float*)d_in[9];
    const float* b4 = (const float*)d_in[10];

    const int N = N_NODES, E = N_EDGES;
    const int* src = ei;
    const int* dst = ei + E;

    // workspace layout (64B-aligned carve-outs)
    char* base = (char*)d_ws;
    size_t off = 0;
    auto carve = [&](size_t bytes) -> void* {
        off = (off + 63) & ~(size_t)63;
        void* p = base + off;
        off += bytes;
        return p;
    };
    unsigned short* Ta = (unsigned short*)carve((size_t)N * 128 * 2);  // bf16 ping
    unsigned short* Tb = (unsigned short*)carve((size_t)N * 128 * 2);  // bf16 pong
    int* degi = (int*)carve((size_t)N * 4);
    float* dis = (float*)carve((size_t)N * 4);
    int* rowptr = (int*)carve((size_t)(N + 1) * 4);
    int* cursor = (int*)carve((size_t)N * 4);
    int* excl = (int*)carve((size_t)N * 4);
    int* bsum = (int*)carve(256 * 4);
    int* boff = (int*)carve(256 * 4);
    unsigned int* csr = (unsigned int*)carve((size_t)E * 4);  // packed {src:16|f16 norm}
    int* gstart = (int*)carve(65 * 4);
    float* partial = (float*)carve((size_t)N_GRAPHS * P4C * 64 * 4);
    unsigned short* Wp1 = (unsigned short*)carve(128 * 128 * 2);
    unsigned short* Wp2 = (unsigned short*)carve(128 * 128 * 2);
    unsigned short* Wp3 = (unsigned short*)carve(128 * 128 * 2);
    unsigned short* Wp4 = (unsigned short*)carve(128 * 64 * 2);

    hipMemsetAsync(degi, 0, N * sizeof(int), stream);

    // ---- prep: degree+wprep -> 3-kernel scan -> fused csr_fill + mm1 ----
    const int NB = (N + 255) / 256;  // 196
    deg_wprep<<<DEGB4 + 224, 256, 0, stream>>>(dst, degi, E, W1, W2, W3, W4,
                                               Wp1, Wp2, Wp3, Wp4);
    scan_block<<<NB, 256, 0, stream>>>(degi, excl, bsum, dis, N);
    scan_top<<<1, 256, 0, stream>>>(bsum, boff, NB, batch, gstart, N);
    scan_fix<<<NB, 256, 0, stream>>>(excl, boff, rowptr, cursor, N, E);
    csrfill_mm1<<<MM1B + 8 * CSRB, 256, 0, stream>>>(src, dst, dis, cursor, csr, E,
                                                     x, Wp1, Ta, N);

    const int FUS = (N + 15) / 16;  // 3125 (exact)

    // fused agg1 + relu + mm2 -> Tb
    aggmm<128><<<FUS, 512, 0, stream>>>(rowptr, csr, dis, b1, Ta, Wp2, Tb, N);
    // fused agg2 + relu + mm3 -> Ta
    aggmm<128><<<FUS, 512, 0, stream>>>(rowptr, csr, dis, b2, Tb, Wp3, Ta, N);
    // fused agg3 + relu + mm4 -> Tb (F=64)
    aggmm<64><<<FUS, 512, 0, stream>>>(rowptr, csr, dis, b3, Ta, Wp4, Tb, N);

    // fused layer-4 aggregation + mean pool (deterministic chunked reduction)
    pool4<<<N_GRAPHS * P4C, 256, 0, stream>>>(rowptr, csr, dis, Tb, gstart, partial);
    pool_fin4<<<N_GRAPHS, 64, 0, stream>>>(partial, gstart, b4, (float*)d_out);
}

// Round 14
// 168.777 us; speedup vs baseline: 1.0785x; 1.0785x over previous
//
#include <hip/hip_runtime.h>
#include <hip/hip_bf16.h>
#include <hip/hip_fp16.h>

// ---------------- constants ----------------
#define N_NODES 50000
#define N_EDGES 600000
#define N_GRAPHS 64
#define P4C 64  // chunks per graph in fused layer4+pool

typedef __attribute__((ext_vector_type(8))) short bf16x8;
typedef __attribute__((ext_vector_type(4))) float f32x4;

// ---------------- bf16 helpers (round-to-nearest-even) ----------------
__device__ __forceinline__ unsigned short f2bf(float f) {
    unsigned int u = __float_as_uint(f);
    unsigned int r = u + 0x7fffu + ((u >> 16) & 1u);
    return (unsigned short)(r >> 16);
}
__device__ __forceinline__ float bf_lo(unsigned int u) { return __uint_as_float(u << 16); }
__device__ __forceinline__ float bf_hi(unsigned int u) { return __uint_as_float(u & 0xffff0000u); }
__device__ __forceinline__ float bf1(unsigned short s) {
    return __uint_as_float((unsigned int)s << 16);
}
// packed csr entry: (src << 16) | f16(norm)
__device__ __forceinline__ float pnorm(unsigned int e) {
    return __half2float(__ushort_as_half((unsigned short)(e & 0xffffu)));
}

// ---------------- fused degree count (+ epos capture) + weight repack ----------------
__device__ __forceinline__ void wprep_one(const float* W, unsigned short* Wp, int F, int idx) {
    int i = idx & 7;
    int lane = (idx >> 3) & 63;
    int ks = (idx >> 9) & 3;
    int ct = idx >> 11;
    int k = ks * 32 + (lane >> 4) * 8 + i;
    int col = ct * 16 + (lane & 15);
    Wp[idx] = f2bf(W[(size_t)k * F + col]);
}

#define DEGB4 ((N_EDGES + 1023) / 1024)  // 586 (4 edges per thread)

__global__ __launch_bounds__(256) void deg_wprep(const int* __restrict__ dst,
                                                 int* __restrict__ degi,
                                                 unsigned short* __restrict__ epos, int E,
                                                 const float* __restrict__ W1,
                                                 const float* __restrict__ W2,
                                                 const float* __restrict__ W3,
                                                 const float* __restrict__ W4,
                                                 unsigned short* __restrict__ Wp1,
                                                 unsigned short* __restrict__ Wp2,
                                                 unsigned short* __restrict__ Wp3,
                                                 unsigned short* __restrict__ Wp4) {
    int bid = blockIdx.x;
    if (bid < DEGB4) {
        int i4 = bid * 1024 + threadIdx.x * 4;
        if (i4 + 4 <= E) {
            int4 d = *reinterpret_cast<const int4*>(dst + i4);
            ushort4 p;
            p.x = (unsigned short)atomicAdd(&degi[d.x], 1);
            p.y = (unsigned short)atomicAdd(&degi[d.y], 1);
            p.z = (unsigned short)atomicAdd(&degi[d.z], 1);
            p.w = (unsigned short)atomicAdd(&degi[d.w], 1);
            *reinterpret_cast<ushort4*>(epos + i4) = p;
        } else {
            for (int i = i4; i < E; ++i)
                epos[i] = (unsigned short)atomicAdd(&degi[dst[i]], 1);
        }
    } else {
        int wb = bid - DEGB4;
        if (wb < 64) wprep_one(W1, Wp1, 128, wb * 256 + threadIdx.x);
        else if (wb < 128) wprep_one(W2, Wp2, 128, (wb - 64) * 256 + threadIdx.x);
        else if (wb < 192) wprep_one(W3, Wp3, 128, (wb - 128) * 256 + threadIdx.x);
        else wprep_one(W4, Wp4, 64, (wb - 192) * 256 + threadIdx.x);
    }
}

// ---------------- prefix scan (3-kernel hierarchical; proven ~8us) ----------------
__global__ __launch_bounds__(256) void scan_block(const int* __restrict__ in,
                                                  int* __restrict__ excl,
                                                  int* __restrict__ bsum,
                                                  float* __restrict__ dis, int N) {
    __shared__ int s[256];
    int i = blockIdx.x * 256 + threadIdx.x;
    int v = (i < N) ? in[i] : 0;
    s[threadIdx.x] = v;
    __syncthreads();
#pragma unroll
    for (int off = 1; off < 256; off <<= 1) {
        int t = (threadIdx.x >= off) ? s[threadIdx.x - off] : 0;
        __syncthreads();
        s[threadIdx.x] += t;
        __syncthreads();
    }
    if (i < N) {
        excl[i] = s[threadIdx.x] - v;
        dis[i] = rsqrtf((float)v + 1.0f);
    }
    if (threadIdx.x == 255) bsum[blockIdx.x] = s[255];
}

__global__ __launch_bounds__(256) void scan_top(const int* __restrict__ bsum,
                                                int* __restrict__ boff, int NB,
                                                const int* __restrict__ batch,
                                                int* __restrict__ gstart, int N) {
    __shared__ int s[256];
    int v = (threadIdx.x < NB) ? bsum[threadIdx.x] : 0;
    s[threadIdx.x] = v;
    __syncthreads();
#pragma unroll
    for (int off = 1; off < 256; off <<= 1) {
        int t = (threadIdx.x >= off) ? s[threadIdx.x - off] : 0;
        __syncthreads();
        s[threadIdx.x] += t;
        __syncthreads();
    }
    if (threadIdx.x < NB) boff[threadIdx.x] = s[threadIdx.x] - v;

    int g = threadIdx.x;
    if (g <= N_GRAPHS) {
        int lo = 0, hi = N;
        while (lo < hi) {
            int mid = (lo + hi) >> 1;
            if (batch[mid] < g) lo = mid + 1; else hi = mid;
        }
        gstart[g] = lo;
    }
}

__global__ __launch_bounds__(256) void scan_fix(const int* __restrict__ excl,
                                                const int* __restrict__ boff,
                                                int* __restrict__ rowptr, int N, int E) {
    int i = blockIdx.x * 256 + threadIdx.x;
    if (i < N) rowptr[i] = excl[i] + boff[blockIdx.x];
    if (i == 0) rowptr[N] = E;
}

// ---------------- FUSED: mm1 + XCD-partitioned ATOMIC-FREE CSR fill ----------------
// csr slot = rowptr[dst] + epos[e] (epos captured in the degree pass).
// XCD partitioning (8 blocks/chunk, dst-range match) keeps each csr line's
// writes within one XCD's L2 -> single writeback, no cross-XCD ping-pong.
#define MM1B ((N_NODES + 63) / 64)        // 782
#define CSRB ((N_EDGES + 255) / 256)      // 2344

__global__ __launch_bounds__(256) void csrfill_mm1(const int* __restrict__ src,
                                                   const int* __restrict__ dst,
                                                   const float* __restrict__ dis,
                                                   const int* __restrict__ rowptr,
                                                   const unsigned short* __restrict__ epos,
                                                   unsigned int* __restrict__ csr, int E,
                                                   const float* __restrict__ Xf,
                                                   const unsigned short* __restrict__ Wp,
                                                   unsigned short* __restrict__ T, int N) {
    if (blockIdx.x >= MM1B) {
        // ---- CSR fill (partitioned, no atomics) ----
        const int part = blockIdx.x & 7;
        const int ch = (blockIdx.x - MM1B) >> 3;
        int e = ch * 256 + threadIdx.x;
        if (e >= E) return;
        int d = dst[e];
        if ((d * 8) / N_NODES != part) return;
        int s = src[e];
        float nrm = dis[s] * dis[d];
        unsigned short hb = __half_as_ushort(__float2half(nrm));
        int pos = rowptr[d] + (int)epos[e];
        csr[pos] = ((unsigned int)s << 16) | (unsigned int)hb;
        return;
    }
    // ---- mm1 ----
    const int lane = threadIdx.x & 63;
    const int wave = threadIdx.x >> 6;
    const int r0 = blockIdx.x * 64 + wave * 16;
    const int kg = lane >> 4;
    const int rdrow = min(r0 + (lane & 15), N - 1);
    const float* xr = Xf + (size_t)rdrow * 128;

    bf16x8 a[4];
#pragma unroll
    for (int ks = 0; ks < 4; ++ks) {
        const int kb = ks * 32 + kg * 8;
        float4 x0 = *reinterpret_cast<const float4*>(xr + kb);
        float4 x1 = *reinterpret_cast<const float4*>(xr + kb + 4);
        float v[8] = {x0.x, x0.y, x0.z, x0.w, x1.x, x1.y, x1.z, x1.w};
#pragma unroll
        for (int i = 0; i < 8; ++i) a[ks][i] = (short)f2bf(v[i]);
    }

#pragma unroll
    for (int ct = 0; ct < 8; ++ct) {
        f32x4 acc = {0.f, 0.f, 0.f, 0.f};
#pragma unroll
        for (int ks = 0; ks < 4; ++ks) {
            bf16x8 b = *reinterpret_cast<const bf16x8*>(Wp + ((size_t)(ct * 4 + ks) * 64 + lane) * 8);
            acc = __builtin_amdgcn_mfma_f32_16x16x32_bf16(a[ks], b, acc, 0, 0, 0);
        }
        const int col = ct * 16 + (lane & 15);
#pragma unroll
        for (int r = 0; r < 4; ++r) {
            const int rowm = r0 + kg * 4 + r;
            if (rowm < N) T[(size_t)rowm * 128 + col] = f2bf(acc[r]);
        }
    }
}

// ---------------- dual-node combined-stream gather (128-feat rows) ----------------
__device__ __forceinline__ void gather128x2(int beg, int mid, int end,
                                            const unsigned int* __restrict__ csr,
                                            const unsigned short* __restrict__ T, int lane,
                                            float& ax0, float& ay0, float& ax1, float& ay1) {
    int p = beg;
    for (; p + 8 <= end; p += 8) {
        unsigned int e0 = csr[p], e1 = csr[p + 1], e2 = csr[p + 2], e3 = csr[p + 3];
        unsigned int e4 = csr[p + 4], e5 = csr[p + 5], e6 = csr[p + 6], e7 = csr[p + 7];
        unsigned int r0 = *reinterpret_cast<const unsigned int*>(T + (size_t)(e0 >> 16) * 128 + lane * 2);
        unsigned int r1 = *reinterpret_cast<const unsigned int*>(T + (size_t)(e1 >> 16) * 128 + lane * 2);
        unsigned int r2 = *reinterpret_cast<const unsigned int*>(T + (size_t)(e2 >> 16) * 128 + lane * 2);
        unsigned int r3 = *reinterpret_cast<const unsigned int*>(T + (size_t)(e3 >> 16) * 128 + lane * 2);
        unsigned int r4 = *reinterpret_cast<const unsigned int*>(T + (size_t)(e4 >> 16) * 128 + lane * 2);
        unsigned int r5 = *reinterpret_cast<const unsigned int*>(T + (size_t)(e5 >> 16) * 128 + lane * 2);
        unsigned int r6 = *reinterpret_cast<const unsigned int*>(T + (size_t)(e6 >> 16) * 128 + lane * 2);
        unsigned int r7 = *reinterpret_cast<const unsigned int*>(T + (size_t)(e7 >> 16) * 128 + lane * 2);
#define ACC8(K)                                                                  \
        {                                                                        \
            float n = pnorm(e##K);                                               \
            float na = (p + K < mid) ? n : 0.0f;                                 \
            float nb = (p + K < mid) ? 0.0f : n;                                 \
            ax0 = fmaf(na, bf_lo(r##K), ax0); ay0 = fmaf(na, bf_hi(r##K), ay0);  \
            ax1 = fmaf(nb, bf_lo(r##K), ax1); ay1 = fmaf(nb, bf_hi(r##K), ay1);  \
        }
        ACC8(0) ACC8(1) ACC8(2) ACC8(3) ACC8(4) ACC8(5) ACC8(6) ACC8(7)
#undef ACC8
    }
    for (; p + 4 <= end; p += 4) {
        unsigned int e0 = csr[p], e1 = csr[p + 1], e2 = csr[p + 2], e3 = csr[p + 3];
        unsigned int r0 = *reinterpret_cast<const unsigned int*>(T + (size_t)(e0 >> 16) * 128 + lane * 2);
        unsigned int r1 = *reinterpret_cast<const unsigned int*>(T + (size_t)(e1 >> 16) * 128 + lane * 2);
        unsigned int r2 = *reinterpret_cast<const unsigned int*>(T + (size_t)(e2 >> 16) * 128 + lane * 2);
        unsigned int r3 = *reinterpret_cast<const unsigned int*>(T + (size_t)(e3 >> 16) * 128 + lane * 2);
#define ACC4(K)                                                                  \
        {                                                                        \
            float n = pnorm(e##K);                                               \
            float na = (p + K < mid) ? n : 0.0f;                                 \
            float nb = (p + K < mid) ? 0.0f : n;                                 \
            ax0 = fmaf(na, bf_lo(r##K), ax0); ay0 = fmaf(na, bf_hi(r##K), ay0);  \
            ax1 = fmaf(nb, bf_lo(r##K), ax1); ay1 = fmaf(nb, bf_hi(r##K), ay1);  \
        }
        ACC4(0) ACC4(1) ACC4(2) ACC4(3)
#undef ACC4
    }
    for (; p < end; ++p) {
        unsigned int e = csr[p];
        unsigned int r = *reinterpret_cast<const unsigned int*>(T + (size_t)(e >> 16) * 128 + lane * 2);
        float n = pnorm(e);
        float na = (p < mid) ? n : 0.0f;
        float nb = (p < mid) ? 0.0f : n;
        ax0 = fmaf(na, bf_lo(r), ax0); ay0 = fmaf(na, bf_hi(r), ay0);
        ax1 = fmaf(nb, bf_lo(r), ax1); ay1 = fmaf(nb, bf_hi(r), ay1);
    }
}

// ---------------- FUSED: agg(layer i) + relu + mm(layer i+1) ----------------
template <int FOUT>
__global__ __launch_bounds__(512) void aggmm(const int* __restrict__ rowptr,
                                             const unsigned int* __restrict__ csr,
                                             const float* __restrict__ dis,
                                             const float* __restrict__ b,
                                             const unsigned short* __restrict__ T,
                                             const unsigned short* __restrict__ Wp,
                                             unsigned short* __restrict__ Tout, int N) {
    __shared__ unsigned short hl[16][136];
    const int lane = threadIdx.x & 63;
    const int wave = threadIdx.x >> 6;
    const int r0 = blockIdx.x * 16;
    const float2 bb = *reinterpret_cast<const float2*>(b + lane * 2);

    const int n0 = __builtin_amdgcn_readfirstlane(r0 + wave * 2);
    const int beg = rowptr[n0];
    const int mid = rowptr[n0 + 1];
    const int end = rowptr[n0 + 2];
    const float d0 = dis[n0], d1 = dis[n0 + 1];

    unsigned int s0 = *reinterpret_cast<const unsigned int*>(T + (size_t)n0 * 128 + lane * 2);
    unsigned int s1 = *reinterpret_cast<const unsigned int*>(T + (size_t)(n0 + 1) * 128 + lane * 2);
    float ax0 = fmaf(bf_lo(s0), d0 * d0, bb.x);
    float ay0 = fmaf(bf_hi(s0), d0 * d0, bb.y);
    float ax1 = fmaf(bf_lo(s1), d1 * d1, bb.x);
    float ay1 = fmaf(bf_hi(s1), d1 * d1, bb.y);

    gather128x2(beg, mid, end, csr, T, lane, ax0, ay0, ax1, ay1);

    *reinterpret_cast<unsigned int*>(&hl[wave * 2 + 0][lane * 2]) =
        ((unsigned int)f2bf(ay0) << 16) | (unsigned int)f2bf(ax0);
    *reinterpret_cast<unsigned int*>(&hl[wave * 2 + 1][lane * 2]) =
        ((unsigned int)f2bf(ay1) << 16) | (unsigned int)f2bf(ax1);
    __syncthreads();

    constexpr int NCT = FOUT / 16;  // 8 (F=128) or 4 (F=64)
    if (wave < NCT) {
        const int kg = lane >> 4;
        bf16x8 a[4];
#pragma unroll
        for (int ks = 0; ks < 4; ++ks) {
            bf16x8 av = *reinterpret_cast<const bf16x8*>(&hl[lane & 15][ks * 32 + kg * 8]);
#pragma unroll
            for (int i = 0; i < 8; ++i) av[i] = (av[i] < 0) ? (short)0 : av[i];
            a[ks] = av;
        }

        const int ct = wave;
        f32x4 acc = {0.f, 0.f, 0.f, 0.f};
#pragma unroll
        for (int ks = 0; ks < 4; ++ks) {
            bf16x8 bfr = *reinterpret_cast<const bf16x8*>(Wp + ((size_t)(ct * 4 + ks) * 64 + lane) * 8);
            acc = __builtin_amdgcn_mfma_f32_16x16x32_bf16(a[ks], bfr, acc, 0, 0, 0);
        }
        const int col = ct * 16 + (lane & 15);
#pragma unroll
        for (int r = 0; r < 4; ++r) {
            Tout[(size_t)(r0 + kg * 4 + r) * FOUT + col] = f2bf(acc[r]);
        }
    }
}

// ---------------- FUSED layer-4 agg + mean pool (algebraic fusion) ----------------
__global__ __launch_bounds__(256) void pool4(const int* __restrict__ rowptr,
                                             const unsigned int* __restrict__ csr,
                                             const float* __restrict__ dis,
                                             const unsigned short* __restrict__ T,
                                             const int* __restrict__ gstart,
                                             float* __restrict__ partial) {
    const int g = blockIdx.x / P4C;
    const int c = blockIdx.x % P4C;
    const int lane = threadIdx.x & 63;
    const int wave = threadIdx.x >> 6;
    const int nb = gstart[g], ne = gstart[g + 1];

    float acc = 0.0f;

    // self-loop part: chunk the node range
    {
        const int len = ne - nb;
        const int cs = (len + P4C - 1) / P4C;
        const int a = nb + c * cs;
        const int bnd = min(a + cs, ne);
        for (int n = a + wave; n < bnd; n += 4) {
            float d = dis[n];
            acc = fmaf(bf1(T[(size_t)n * 64 + lane]) * d, d, acc);
        }
    }

    // edge part: chunk the graph's contiguous edge range
    {
        const int eb = rowptr[nb], ee = rowptr[ne];
        const int len = ee - eb;
        const int cs = (len + P4C - 1) / P4C;
        const int a = eb + c * cs;
        const int bnd = min(a + cs, ee);
        int p = a + wave;
        for (; p + 8 * 4 <= bnd; p += 32) {
            unsigned int e0 = csr[p], e1 = csr[p + 4], e2 = csr[p + 8], e3 = csr[p + 12];
            unsigned int e4 = csr[p + 16], e5 = csr[p + 20], e6 = csr[p + 24], e7 = csr[p + 28];
            unsigned short v0 = T[(size_t)(e0 >> 16) * 64 + lane];
            unsigned short v1 = T[(size_t)(e1 >> 16) * 64 + lane];
            unsigned short v2 = T[(size_t)(e2 >> 16) * 64 + lane];
            unsigned short v3 = T[(size_t)(e3 >> 16) * 64 + lane];
            unsigned short v4 = T[(size_t)(e4 >> 16) * 64 + lane];
            unsigned short v5 = T[(size_t)(e5 >> 16) * 64 + lane];
            unsigned short v6 = T[(size_t)(e6 >> 16) * 64 + lane];
            unsigned short v7 = T[(size_t)(e7 >> 16) * 64 + lane];
            acc = fmaf(pnorm(e0), bf1(v0), acc);
            acc = fmaf(pnorm(e1), bf1(v1), acc);
            acc = fmaf(pnorm(e2), bf1(v2), acc);
            acc = fmaf(pnorm(e3), bf1(v3), acc);
            acc = fmaf(pnorm(e4), bf1(v4), acc);
            acc = fmaf(pnorm(e5), bf1(v5), acc);
            acc = fmaf(pnorm(e6), bf1(v6), acc);
            acc = fmaf(pnorm(e7), bf1(v7), acc);
        }
        for (; p < bnd; p += 4) {
            unsigned int e = csr[p];
            acc = fmaf(pnorm(e), bf1(T[(size_t)(e >> 16) * 64 + lane]), acc);
        }
    }

    __shared__ float s[4][64];
    s[wave][lane] = acc;
    __syncthreads();
    if (wave == 0)
        partial[(size_t)blockIdx.x * 64 + lane] =
            s[0][lane] + s[1][lane] + s[2][lane] + s[3][lane];
}

__global__ __launch_bounds__(64) void pool_fin4(const float* __restrict__ partial,
                                                const int* __restrict__ gstart,
                                                const float* __restrict__ b4,
                                                float* __restrict__ out) {
    const int g = blockIdx.x;
    const int lane = threadIdx.x;
    float v = 0.0f;
#pragma unroll 8
    for (int c = 0; c < P4C; ++c) v += partial[(size_t)(g * P4C + c) * 64 + lane];
    float cnt = (float)(gstart[g + 1] - gstart[g]);
    v += cnt * b4[lane];
    out[g * 64 + lane] = v / fmaxf(cnt, 1.0f);
}

// ---------------- launch ----------------
extern "C" void kernel_launch(void* const* d_in, const int* in_sizes, int n_in,
                              void* d_out, int out_size, void* d_ws, size_t ws_size,
                              hipStream_t stream) {
    const float* x = (const float*)d_in[0];
    const int* ei = (const int*)d_in[1];
    const int* batch = (const int*)d_in[2];
    const float* W1 = (const float*)d_in[3];
    const float* b1 = (const float*)d_in[4];
    const float* W2 = (const float*)d_in[5];
    const float* b2 = (const float*)d_in[6];
    const float* W3 = (const float*)d_in[7];
    const float* b3 = (const float*)d_in[8];
    const float* W4 = (const float*)d_in[9];
    const float* b4 = (const float*)d_in[10];

    const int N = N_NODES, E = N_EDGES;
    const int* src = ei;
    const int* dst = ei + E;

    // workspace layout (64B-aligned carve-outs)
    char* base = (char*)d_ws;
    size_t off = 0;
    auto carve = [&](size_t bytes) -> void* {
        off = (off + 63) & ~(size_t)63;
        void* p = base + off;
        off += bytes;
        return p;
    };
    unsigned short* Ta = (unsigned short*)carve((size_t)N * 128 * 2);  // bf16 ping
    unsigned short* Tb = (unsigned short*)carve((size_t)N * 128 * 2);  // bf16 pong
    int* degi = (int*)carve((size_t)N * 4);
    float* dis = (float*)carve((size_t)N * 4);
    int* rowptr = (int*)carve((size_t)(N + 1) * 4);
    int* excl = (int*)carve((size_t)N * 4);
    int* bsum = (int*)carve(256 * 4);
    int* boff = (int*)carve(256 * 4);
    unsigned short* epos = (unsigned short*)carve((size_t)E * 2);  // per-edge slot
    unsigned int* csr = (unsigned int*)carve((size_t)E * 4);       // packed {src:16|f16}
    int* gstart = (int*)carve(65 * 4);
    float* partial = (float*)carve((size_t)N_GRAPHS * P4C * 64 * 4);
    unsigned short* Wp1 = (unsigned short*)carve(128 * 128 * 2);
    unsigned short* Wp2 = (unsigned short*)carve(128 * 128 * 2);
    unsigned short* Wp3 = (unsigned short*)carve(128 * 128 * 2);
    unsigned short* Wp4 = (unsigned short*)carve(128 * 64 * 2);

    hipMemsetAsync(degi, 0, N * sizeof(int), stream);

    // ---- prep: degree(+epos)+wprep -> 3-kernel scan -> atomic-free csr_fill + mm1 ----
    const int NB = (N + 255) / 256;  // 196
    deg_wprep<<<DEGB4 + 224, 256, 0, stream>>>(dst, degi, epos, E, W1, W2, W3, W4,
                                               Wp1, Wp2, Wp3, Wp4);
    scan_block<<<NB, 256, 0, stream>>>(degi, excl, bsum, dis, N);
    scan_top<<<1, 256, 0, stream>>>(bsum, boff, NB, batch, gstart, N);
    scan_fix<<<NB, 256, 0, stream>>>(excl, boff, rowptr, N, E);
    csrfill_mm1<<<MM1B + 8 * CSRB, 256, 0, stream>>>(src, dst, dis, rowptr, epos, csr, E,
                                                     x, Wp1, Ta, N);

    const int FUS = (N + 15) / 16;  // 3125 (exact)

    // fused agg1 + relu + mm2 -> Tb
    aggmm<128><<<FUS, 512, 0, stream>>>(rowptr, csr, dis, b1, Ta, Wp2, Tb, N);
    // fused agg2 + relu + mm3 -> Ta
    aggmm<128><<<FUS, 512, 0, stream>>>(rowptr, csr, dis, b2, Tb, Wp3, Ta, N);
    // fused agg3 + relu + mm4 -> Tb (F=64)
    aggmm<64><<<FUS, 512, 0, stream>>>(rowptr, csr, dis, b3, Ta, Wp4, Tb, N);

    // fused layer-4 aggregation + mean pool (deterministic chunked reduction)
    pool4<<<N_GRAPHS * P4C, 256, 0, stream>>>(rowptr, csr, dis, Tb, gstart, partial);
    pool_fin4<<<N_GRAPHS, 64, 0, stream>>>(partial, gstart, b4, (float*)d_out);
}